// Round 3
// baseline (347.783 us; speedup 1.0000x reference)
//
#include <hip/hip_runtime.h>

#define IMG 4
// x rows padded to 36 floats: float4-aligned rows, row->bank shift of 4.
#define XSTR  36
#define XIMG  (32 * XSTR)        // 1152 floats per image
#define S2STR 15                 // s2 row stride (15%32 -> near-conflict-free scalar reads)
#define S2MAP (14 * S2STR)       // 210
#define S2IMG (6 * S2MAP)        // 1260

// ---- LDS layout (floats) ----
// Region A [0..4608): phase1 = x (4 x 32 x 36)
//                     phase2+ = c3w[0..1500) | s4 @1504 (1600) | c5o @3104 (480) | f6 @3584 (336)
#define A_SIZE   (IMG * XIMG)                // 4608
#define S4_OFF   1504
#define C5O_OFF  3104
#define F6_OFF   3584
#define S2_OFF   A_SIZE                      // 4608, size 4*1260 = 5040
#define C1W_OFF  (S2_OFF + IMG * S2IMG)      // 9648, size 150 (+2 pad)
#define C1B_OFF  (C1W_OFF + 152)             // 9800, size 6 (+2)
#define C3B_OFF  (C1B_OFF + 8)               // 9808, size 16
#define SMEM_FLOATS (C3B_OFF + 16)           // 9824 floats = 39,296 B -> 4 blocks/CU

// ---- LeNet C3 sparse connectivity ----
__device__ __constant__ int C3_NCH[16]  = {3,3,3,3,3,3, 4,4,4,4,4,4,4,4,4, 6};
__device__ __constant__ int C3_WOFF[16] = {0,75,150,225,300,375,
                                           450,550,650,750,850,950,1050,1150,1250,
                                           1350};
__device__ __constant__ int C3_CH[16][6] = {
    {0,1,2,0,0,0},{1,2,3,0,0,0},{2,3,4,0,0,0},{3,4,5,0,0,0},{0,4,5,0,0,0},{0,1,5,0,0,0},
    {0,1,2,3,0,0},{1,2,3,4,0,0},{2,3,4,5,0,0},{0,3,4,5,0,0},{0,1,4,5,0,0},
    {0,1,2,5,0,0},{0,1,3,4,0,0},{1,2,4,5,0,0},{0,2,3,5,0,0},
    {0,1,2,3,4,5}
};

__device__ __forceinline__ float fast_tanh(float x) {
    // tanh(x) = 1 - 2/(e^{2x}+1); saturates to +/-1, no NaN.
    float e = __expf(2.0f * x);
    return 1.0f - 2.0f / (e + 1.0f);
}

// NOTE: plain launch_bounds. (256,4) forced VGPR=64 -> scratch spills
// (WRITE_SIZE 0.33->4.2 MB, round 2). LDS (39.3 KB) caps us at 4 blocks/CU
// anyway, so VGPR up to 128 costs nothing.
__global__ __launch_bounds__(256) void lenet_fused(
    const float* __restrict__ x,
    const float* __restrict__ c1_w,  const float* __restrict__ c1_b,
    const float* __restrict__ c3_w3, const float* __restrict__ c3_b3,
    const float* __restrict__ c3_w4, const float* __restrict__ c3_b4,
    const float* __restrict__ c3_w6, const float* __restrict__ c3_b6,
    const float* __restrict__ c5_w,  const float* __restrict__ c5_b,
    const float* __restrict__ l1_w,  const float* __restrict__ l1_b,
    const float* __restrict__ l2_w,  const float* __restrict__ l2_b,
    float* __restrict__ out, int B)
{
    __shared__ __align__(16) float smem[SMEM_FLOATS];
    float* x_s   = smem;                 // phase 1 only
    float* c3w_s = smem;                 // phase 2+ (aliases x_s)
    float* s4_s  = smem + S4_OFF;
    float* c5o_s = smem + C5O_OFF;
    float* f6_s  = smem + F6_OFF;
    float* s2_s  = smem + S2_OFF;
    float* c1w_s = smem + C1W_OFF;
    float* c1b_s = smem + C1B_OFF;
    float* c3b_s = smem + C3B_OFF;

    const int tid  = threadIdx.x;
    const int img0 = blockIdx.x * IMG;
    const int nimg = min(IMG, B - img0);
    if (nimg <= 0) return;

    // ---- prefetch c3 weights into registers (consumed after C1) ----
    float c3wr[6];
    const int c3base = tid * 6;
    #pragma unroll
    for (int j = 0; j < 6; ++j) {
        int idx = c3base + j;
        float v = 0.0f;
        if (idx < 450)        v = c3_w3[idx];
        else if (idx < 1350)  v = c3_w4[idx - 450];
        else if (idx < 1500)  v = c3_w6[idx - 1350];
        c3wr[j] = v;
    }

    // ---- stage small persistent weights ----
    for (int i = tid; i < 150; i += 256) c1w_s[i] = c1_w[i];
    if (tid < 6) c1b_s[tid] = c1_b[tid];
    if (tid < 6)        c3b_s[tid] = c3_b3[tid];
    else if (tid < 15)  c3b_s[tid] = c3_b4[tid - 6];
    else if (tid == 15) c3b_s[15]  = c3_b6[0];

    // ---- stage x into padded LDS (coalesced float4 both sides) ----
    {
        const float4* xg = (const float4*)(x + (size_t)img0 * 1024);
        const int n4 = nimg * 256;
        for (int i = tid; i < n4; i += 256) {
            float4 v = xg[i];
            int img = i >> 8, q = i & 255;
            int row = q >> 3, col4 = (q & 7) << 2;
            *(float4*)(x_s + img * XIMG + row * XSTR + col4) = v;
        }
    }
    __syncthreads();

    // ---- C1 (5x5 conv) + tanh + 2x2 avgpool -> s2 [img][6][14 x S2STR] ----
    // work item = (img, c, pooled-row i, half h). h is made WAVE-UNIFORM
    // (bit 6 of the index) so the alignment branch below is exec-mask-cheap
    // and each arm uses compile-time-aligned float4/float2 LDS reads.
    {
        const int perh = nimg * 84;                  // items per half (336)
        const int dom  = ((perh + 63) >> 6) << 7;    // 2 * ceil64(perh) * 64
        for (int it = tid; it < dom; it += 256) {
            const int h    = (it >> 6) & 1;
            const int rest = ((it >> 7) << 6) | (it & 63);
            if (rest >= perh) continue;
            int i   = rest % 14;
            int t3  = rest / 14;
            int c   = t3 % 6;
            int img = t3 / 6;
            const float* xb = x_s + img * XIMG;
            float w[25];
            #pragma unroll
            for (int k = 0; k < 25; ++k) w[k] = c1w_s[c * 25 + k];
            float acc[2][14];
            #pragma unroll
            for (int a = 0; a < 2; ++a)
                #pragma unroll
                for (int j = 0; j < 14; ++j) acc[a][j] = 0.0f;
            #pragma unroll
            for (int xr = 0; xr < 6; ++xr) {
                const float* rp = xb + (2 * i + xr) * XSTR;   // float4-aligned
                float row[18];
                if (h == 0) {         // cols [0,18)
                    float4 a0 = *(const float4*)(rp);
                    float4 a1 = *(const float4*)(rp + 4);
                    float4 a2 = *(const float4*)(rp + 8);
                    float4 a3 = *(const float4*)(rp + 12);
                    float2 a4 = *(const float2*)(rp + 16);
                    row[0]=a0.x; row[1]=a0.y; row[2]=a0.z; row[3]=a0.w;
                    row[4]=a1.x; row[5]=a1.y; row[6]=a1.z; row[7]=a1.w;
                    row[8]=a2.x; row[9]=a2.y; row[10]=a2.z; row[11]=a2.w;
                    row[12]=a3.x; row[13]=a3.y; row[14]=a3.z; row[15]=a3.w;
                    row[16]=a4.x; row[17]=a4.y;
                } else {              // cols [14,32)
                    float2 a0 = *(const float2*)(rp + 14);
                    float4 a1 = *(const float4*)(rp + 16);
                    float4 a2 = *(const float4*)(rp + 20);
                    float4 a3 = *(const float4*)(rp + 24);
                    float4 a4 = *(const float4*)(rp + 28);
                    row[0]=a0.x; row[1]=a0.y;
                    row[2]=a1.x; row[3]=a1.y; row[4]=a1.z; row[5]=a1.w;
                    row[6]=a2.x; row[7]=a2.y; row[8]=a2.z; row[9]=a2.w;
                    row[10]=a3.x; row[11]=a3.y; row[12]=a3.z; row[13]=a3.w;
                    row[14]=a4.x; row[15]=a4.y; row[16]=a4.z; row[17]=a4.w;
                }
                #pragma unroll
                for (int di = 0; di < 2; ++di) {
                    const int u = xr - di;
                    if (u >= 0 && u <= 4) {
                        #pragma unroll
                        for (int j = 0; j < 14; ++j)
                            #pragma unroll
                            for (int v = 0; v < 5; ++v)
                                acc[di][j] = fmaf(row[j + v], w[u * 5 + v], acc[di][j]);
                    }
                }
            }
            const float b = c1b_s[c];
            float* o = s2_s + img * S2IMG + c * S2MAP + i * S2STR + 7 * h;
            #pragma unroll
            for (int j = 0; j < 7; ++j) {
                float t00 = fast_tanh(acc[0][2 * j]     + b);
                float t01 = fast_tanh(acc[0][2 * j + 1] + b);
                float t10 = fast_tanh(acc[1][2 * j]     + b);
                float t11 = fast_tanh(acc[1][2 * j + 1] + b);
                o[j] = 0.25f * (t00 + t01 + t10 + t11);
            }
        }
    }
    __syncthreads();

    // ---- x_s is dead: store prefetched c3 weights into region A ----
    #pragma unroll
    for (int j = 0; j < 6; ++j) {
        int idx = c3base + j;
        if (idx < 1500) c3w_s[idx] = c3wr[j];
    }
    __syncthreads();

    // ---- C3 sparse conv + tanh + pool -> s4 [img][16][5][5] ----
    for (int it = tid; it < nimg * 80; it += 256) {
        int i   = it % 5;
        int t2  = it / 5;
        int m   = t2 % 16;
        int img = t2 / 16;
        const int n = C3_NCH[m];
        const float* wb = c3w_s + C3_WOFF[m];
        float acc[2][10];
        #pragma unroll
        for (int a = 0; a < 2; ++a)
            #pragma unroll
            for (int j = 0; j < 10; ++j) acc[a][j] = 0.0f;
        for (int cc = 0; cc < n; ++cc) {
            const int c = C3_CH[m][cc];
            float w[25];
            #pragma unroll
            for (int k = 0; k < 25; ++k) w[k] = wb[cc * 25 + k];
            const float* sb = s2_s + img * S2IMG + c * S2MAP;
            #pragma unroll
            for (int xr = 0; xr < 6; ++xr) {
                float row[14];
                const float* rp = sb + (2 * i + xr) * S2STR;
                #pragma unroll
                for (int k = 0; k < 14; ++k) row[k] = rp[k];
                #pragma unroll
                for (int di = 0; di < 2; ++di) {
                    const int u = xr - di;
                    if (u >= 0 && u <= 4) {
                        #pragma unroll
                        for (int j = 0; j < 10; ++j)
                            #pragma unroll
                            for (int v = 0; v < 5; ++v)
                                acc[di][j] = fmaf(row[j + v], w[u * 5 + v], acc[di][j]);
                    }
                }
            }
        }
        const float b = c3b_s[m];
        float* o = s4_s + img * 400 + m * 25 + i * 5;
        #pragma unroll
        for (int j = 0; j < 5; ++j) {
            float t00 = fast_tanh(acc[0][2 * j]     + b);
            float t01 = fast_tanh(acc[0][2 * j + 1] + b);
            float t10 = fast_tanh(acc[1][2 * j]     + b);
            float t11 = fast_tanh(acc[1][2 * j + 1] + b);
            o[j] = 0.25f * (t00 + t01 + t10 + t11);
        }
    }
    __syncthreads();

    // ---- C5: FC 400 -> 120, tanh. 2 outputs/thread, float4 streams ----
    for (int it = tid; it < nimg * 60; it += 256) {
        int op  = it % 60;
        int img = it / 60;
        int o0  = op * 2;
        const float4* wa = (const float4*)(c5_w + (size_t)o0 * 400);
        const float4* wb = (const float4*)(c5_w + (size_t)o0 * 400 + 400);
        const float4* sv = (const float4*)(s4_s + img * 400);
        float a0 = 0.0f, a1 = 0.0f;
        #pragma unroll 4
        for (int k = 0; k < 100; ++k) {
            float4 s = sv[k];
            float4 u = wa[k];
            float4 v = wb[k];
            a0 = fmaf(s.x, u.x, a0); a0 = fmaf(s.y, u.y, a0);
            a0 = fmaf(s.z, u.z, a0); a0 = fmaf(s.w, u.w, a0);
            a1 = fmaf(s.x, v.x, a1); a1 = fmaf(s.y, v.y, a1);
            a1 = fmaf(s.z, v.z, a1); a1 = fmaf(s.w, v.w, a1);
        }
        c5o_s[img * 120 + o0]     = fast_tanh(a0 + c5_b[o0]);
        c5o_s[img * 120 + o0 + 1] = fast_tanh(a1 + c5_b[o0 + 1]);
    }
    __syncthreads();

    // ---- F6: FC 120 -> 84, tanh ----
    for (int it = tid; it < nimg * 84; it += 256) {
        int o   = it % 84;
        int img = it / 84;
        const float4* wv = (const float4*)(l1_w + o * 120);
        const float4* cv = (const float4*)(c5o_s + img * 120);
        float a = 0.0f;
        #pragma unroll
        for (int k = 0; k < 30; ++k) {
            float4 u = wv[k];
            float4 s = cv[k];
            a = fmaf(s.x, u.x, a); a = fmaf(s.y, u.y, a);
            a = fmaf(s.z, u.z, a); a = fmaf(s.w, u.w, a);
        }
        f6_s[img * 84 + o] = fast_tanh(a + l1_b[o]);
    }
    __syncthreads();

    // ---- Output: FC 84 -> 10 (no tanh) ----
    for (int it = tid; it < nimg * 10; it += 256) {
        int o   = it % 10;
        int img = it / 10;
        const float4* wv = (const float4*)(l2_w + o * 84);
        const float4* fv = (const float4*)(f6_s + img * 84);
        float a = 0.0f;
        #pragma unroll
        for (int k = 0; k < 21; ++k) {
            float4 u = wv[k];
            float4 s = fv[k];
            a = fmaf(s.x, u.x, a); a = fmaf(s.y, u.y, a);
            a = fmaf(s.z, u.z, a); a = fmaf(s.w, u.w, a);
        }
        out[(size_t)(img0 + img) * 10 + o] = a + l2_b[o];
    }
}

extern "C" void kernel_launch(void* const* d_in, const int* in_sizes, int n_in,
                              void* d_out, int out_size, void* d_ws, size_t ws_size,
                              hipStream_t stream) {
    const float* x     = (const float*)d_in[0];
    const float* c1_w  = (const float*)d_in[1];
    const float* c1_b  = (const float*)d_in[2];
    const float* c3_w3 = (const float*)d_in[3];
    const float* c3_b3 = (const float*)d_in[4];
    const float* c3_w4 = (const float*)d_in[5];
    const float* c3_b4 = (const float*)d_in[6];
    const float* c3_w6 = (const float*)d_in[7];
    const float* c3_b6 = (const float*)d_in[8];
    const float* c5_w  = (const float*)d_in[9];
    const float* c5_b  = (const float*)d_in[10];
    const float* l1_w  = (const float*)d_in[11];
    const float* l1_b  = (const float*)d_in[12];
    const float* l2_w  = (const float*)d_in[13];
    const float* l2_b  = (const float*)d_in[14];
    float* out = (float*)d_out;

    const int B = in_sizes[0] / 1024;   // [B,1,32,32]
    const int grid = (B + IMG - 1) / IMG;
    lenet_fused<<<grid, 256, 0, stream>>>(
        x, c1_w, c1_b, c3_w3, c3_b3, c3_w4, c3_b4, c3_w6, c3_b6,
        c5_w, c5_b, l1_w, l1_b, l2_w, l2_b, out, B);
}

// Round 4
// 314.371 us; speedup vs baseline: 1.1063x; 1.1063x over previous
//
#include <hip/hip_runtime.h>

typedef float v2f __attribute__((ext_vector_type(2)));

#define IMG 3
#define XSTR  33                 // x row stride; scalar reads broadcast per-row
#define XIMG  (32 * XSTR)        // 1056 floats per image
#define S2STR 15                 // s2 row stride
#define S2MAP (14 * S2STR)       // 210
#define S2IMG (6 * S2MAP)        // 1260

// ---- LDS layout (floats) ----
// Region A [0..3344): phase1 = x (3 x 1056 = 3168)
//   phase2+ = c3w[0..1500) | s4 @1504 (1200) | c5o @2704 (360) | f6 @3064 (252)
#define A_SIZE   3344
#define S4_OFF   1504
#define C5O_OFF  2704
#define F6_OFF   3064
#define S2_OFF   A_SIZE                      // 3344, size 3*1260 = 3780
#define C1WP_OFF (S2_OFF + IMG * S2IMG)      // 7124, packed c1 weights, 360
#define C1B_OFF  (C1WP_OFF + 360)            // 7484, 6 (+2)
#define C3B_OFF  (C1B_OFF + 8)               // 7492, 16
#define SMEM_FLOATS (C3B_OFF + 16)           // 7508 floats = 30032 B -> 5 blocks/CU

// ---- LeNet C3 sparse connectivity ----
__device__ __constant__ int C3_NCH[16]  = {3,3,3,3,3,3, 4,4,4,4,4,4,4,4,4, 6};
__device__ __constant__ int C3_WOFF[16] = {0,75,150,225,300,375,
                                           450,550,650,750,850,950,1050,1150,1250,
                                           1350};
__device__ __constant__ int C3_CH[16][6] = {
    {0,1,2,0,0,0},{1,2,3,0,0,0},{2,3,4,0,0,0},{3,4,5,0,0,0},{0,4,5,0,0,0},{0,1,5,0,0,0},
    {0,1,2,3,0,0},{1,2,3,4,0,0},{2,3,4,5,0,0},{0,3,4,5,0,0},{0,1,4,5,0,0},
    {0,1,2,5,0,0},{0,1,3,4,0,0},{1,2,4,5,0,0},{0,2,3,5,0,0},
    {0,1,2,3,4,5}
};

__device__ __forceinline__ float fast_tanh(float x) {
    // tanh(x) = 1 - 2/(e^{2x}+1); saturating, no NaN. rcp: ~1e-7 rel, fine.
    float e = __expf(2.0f * x);
    return fmaf(-2.0f, __builtin_amdgcn_rcpf(e + 1.0f), 1.0f);
}

__device__ __forceinline__ v2f fma2(v2f a, v2f b, v2f c) {
    return __builtin_elementwise_fma(a, b, c);
}

// Plain launch_bounds: forcing min-waves caused spills in round 2.
// LDS 30.0 KB -> 5 blocks/CU if VGPR <= 102.
__global__ __launch_bounds__(256) void lenet_fused(
    const float* __restrict__ x,
    const float* __restrict__ c1_w,  const float* __restrict__ c1_b,
    const float* __restrict__ c3_w3, const float* __restrict__ c3_b3,
    const float* __restrict__ c3_w4, const float* __restrict__ c3_b4,
    const float* __restrict__ c3_w6, const float* __restrict__ c3_b6,
    const float* __restrict__ c5_w,  const float* __restrict__ c5_b,
    const float* __restrict__ l1_w,  const float* __restrict__ l1_b,
    const float* __restrict__ l2_w,  const float* __restrict__ l2_b,
    float* __restrict__ out, int B)
{
    __shared__ __align__(16) float smem[SMEM_FLOATS];
    float* x_s   = smem;                 // phase 1 only
    float* c3w_s = smem;                 // phase 2+ (aliases x_s)
    float* s4_s  = smem + S4_OFF;
    float* c5o_s = smem + C5O_OFF;
    float* f6_s  = smem + F6_OFF;
    float* s2_s  = smem + S2_OFF;
    float* c1wp  = smem + C1WP_OFF;
    float* c1b_s = smem + C1B_OFF;
    float* c3b_s = smem + C3B_OFF;

    const int tid  = threadIdx.x;
    const int img0 = blockIdx.x * IMG;
    const int nimg = min(IMG, B - img0);
    if (nimg <= 0) return;

    // ---- prefetch c3 weights into registers (stored to LDS after C1) ----
    float c3wr[6];
    const int c3base = tid * 6;
    #pragma unroll
    for (int j = 0; j < 6; ++j) {
        int idx = c3base + j;
        float v = 0.0f;
        if (idx < 450)        v = c3_w3[idx];
        else if (idx < 1350)  v = c3_w4[idx - 450];
        else if (idx < 1500)  v = c3_w6[idx - 1350];
        c3wr[j] = v;
    }

    // ---- build packed C1 weights in LDS: pair (c,xr,v) ->
    //      {w[xr*5+v] (di=0), w[(xr-1)*5+v] (di=1)}, zero at edges ----
    if (tid < 180) {
        int c  = tid / 30;
        int rr = tid % 30;
        int xr = rr / 5, v = rr % 5;
        float lo = (xr <= 4) ? c1_w[c * 25 + xr * 5 + v]       : 0.0f;
        float hi = (xr >= 1) ? c1_w[c * 25 + (xr - 1) * 5 + v] : 0.0f;
        c1wp[tid * 2]     = lo;
        c1wp[tid * 2 + 1] = hi;
    }
    if (tid < 6) c1b_s[tid] = c1_b[tid];
    if (tid < 6)        c3b_s[tid] = c3_b3[tid];
    else if (tid < 15)  c3b_s[tid] = c3_b4[tid - 6];
    else if (tid == 15) c3b_s[15]  = c3_b6[0];

    // ---- stage x into LDS ----
    {
        const float4* xg = (const float4*)(x + (size_t)img0 * 1024);
        const int n4 = nimg * 256;
        for (int i = tid; i < n4; i += 256) {
            float4 v = xg[i];
            int img = i >> 8, q = i & 255;
            int row = q >> 3, col4 = (q & 7) << 2;
            float* p = x_s + img * XIMG + row * XSTR + col4;
            p[0] = v.x; p[1] = v.y; p[2] = v.z; p[3] = v.w;
        }
    }
    __syncthreads();

    // ---- C1 + tanh + pool -> s2. item = (img, c, pooled-row i, half h) ----
    // Packed over di (the two conv rows feeding one pooled row).
    for (int it = tid; it < nimg * 168; it += 256) {
        int h   = it & 1;
        int t2  = it >> 1;
        int i   = t2 % 14;
        int t3  = t2 / 14;
        int c   = t3 % 6;
        int img = t3 / 6;
        const float* xb = x_s + img * XIMG;
        v2f acc2[14];
        #pragma unroll
        for (int j = 0; j < 14; ++j) acc2[j] = (v2f){0.0f, 0.0f};
        const int col0 = 14 * h;
        #pragma unroll
        for (int xr = 0; xr < 6; ++xr) {
            float row[18];
            const float* rp = xb + (2 * i + xr) * XSTR + col0;
            #pragma unroll
            for (int k = 0; k < 18; ++k) row[k] = rp[k];   // broadcast reads
            const v2f* wp = (const v2f*)(c1wp + (c * 6 + xr) * 10);
            v2f w0 = wp[0], w1 = wp[1], w2 = wp[2], w3 = wp[3], w4 = wp[4];
            #pragma unroll
            for (int j = 0; j < 14; ++j) {
                acc2[j] = fma2((v2f){row[j],     row[j]},     w0, acc2[j]);
                acc2[j] = fma2((v2f){row[j + 1], row[j + 1]}, w1, acc2[j]);
                acc2[j] = fma2((v2f){row[j + 2], row[j + 2]}, w2, acc2[j]);
                acc2[j] = fma2((v2f){row[j + 3], row[j + 3]}, w3, acc2[j]);
                acc2[j] = fma2((v2f){row[j + 4], row[j + 4]}, w4, acc2[j]);
            }
        }
        const float b = c1b_s[c];
        float* o = s2_s + img * S2IMG + c * S2MAP + i * S2STR + 7 * h;
        #pragma unroll
        for (int j = 0; j < 7; ++j) {
            float t00 = fast_tanh(acc2[2 * j].x     + b);
            float t01 = fast_tanh(acc2[2 * j + 1].x + b);
            float t10 = fast_tanh(acc2[2 * j].y     + b);
            float t11 = fast_tanh(acc2[2 * j + 1].y + b);
            o[j] = 0.25f * (t00 + t01 + t10 + t11);
        }
    }
    __syncthreads();

    // ---- x_s dead: store c3 weights into region A ----
    #pragma unroll
    for (int j = 0; j < 6; ++j) {
        int idx = c3base + j;
        if (idx < 1500) c3w_s[idx] = c3wr[j];
    }
    __syncthreads();

    // ---- C3 sparse + tanh + pool -> s4. Packed over di. ----
    for (int it = tid; it < nimg * 80; it += 256) {
        int i   = it % 5;
        int t2  = it / 5;
        int m   = t2 % 16;
        int img = t2 / 16;
        const int n = C3_NCH[m];
        const float* wb = c3w_s + C3_WOFF[m];
        v2f acc2[10];
        #pragma unroll
        for (int j = 0; j < 10; ++j) acc2[j] = (v2f){0.0f, 0.0f};
        for (int cc = 0; cc < n; ++cc) {
            const int c = C3_CH[m][cc];
            float w[25];
            #pragma unroll
            for (int k = 0; k < 25; ++k) w[k] = wb[cc * 25 + k];
            const float* sb = s2_s + img * S2IMG + c * S2MAP;
            #pragma unroll
            for (int xr = 0; xr < 6; ++xr) {
                float row[14];
                const float* rp = sb + (2 * i + xr) * S2STR;
                #pragma unroll
                for (int k = 0; k < 14; ++k) row[k] = rp[k];
                v2f wp[5];
                #pragma unroll
                for (int v = 0; v < 5; ++v) {
                    wp[v].x = (xr <= 4) ? w[xr * 5 + v]       : 0.0f;
                    wp[v].y = (xr >= 1) ? w[(xr - 1) * 5 + v] : 0.0f;
                }
                #pragma unroll
                for (int j = 0; j < 10; ++j) {
                    acc2[j] = fma2((v2f){row[j],     row[j]},     wp[0], acc2[j]);
                    acc2[j] = fma2((v2f){row[j + 1], row[j + 1]}, wp[1], acc2[j]);
                    acc2[j] = fma2((v2f){row[j + 2], row[j + 2]}, wp[2], acc2[j]);
                    acc2[j] = fma2((v2f){row[j + 3], row[j + 3]}, wp[3], acc2[j]);
                    acc2[j] = fma2((v2f){row[j + 4], row[j + 4]}, wp[4], acc2[j]);
                }
            }
        }
        const float b = c3b_s[m];
        float* o = s4_s + img * 400 + m * 25 + i * 5;
        #pragma unroll
        for (int j = 0; j < 5; ++j) {
            float t00 = fast_tanh(acc2[2 * j].x     + b);
            float t01 = fast_tanh(acc2[2 * j + 1].x + b);
            float t10 = fast_tanh(acc2[2 * j].y     + b);
            float t11 = fast_tanh(acc2[2 * j + 1].y + b);
            o[j] = 0.25f * (t00 + t01 + t10 + t11);
        }
    }
    __syncthreads();

    // ---- C5: FC 400 -> 120, tanh. 2 outputs/thread, packed fp32 ----
    for (int it = tid; it < nimg * 60; it += 256) {
        int op  = it % 60;
        int img = it / 60;
        int o0  = op * 2;
        const float4* wa = (const float4*)(c5_w + (size_t)o0 * 400);
        const float4* wb = (const float4*)(c5_w + (size_t)o0 * 400 + 400);
        const float4* sv = (const float4*)(s4_s + img * 400);
        v2f a2 = (v2f){0.0f, 0.0f}, b2 = (v2f){0.0f, 0.0f};
        #pragma unroll 4
        for (int k = 0; k < 100; ++k) {
            float4 s = sv[k];
            float4 u = wa[k];
            float4 v = wb[k];
            v2f slo = {s.x, s.y}, shi = {s.z, s.w};
            a2 = fma2(slo, (v2f){u.x, u.y}, a2);
            a2 = fma2(shi, (v2f){u.z, u.w}, a2);
            b2 = fma2(slo, (v2f){v.x, v.y}, b2);
            b2 = fma2(shi, (v2f){v.z, v.w}, b2);
        }
        c5o_s[img * 120 + o0]     = fast_tanh(a2.x + a2.y + c5_b[o0]);
        c5o_s[img * 120 + o0 + 1] = fast_tanh(b2.x + b2.y + c5_b[o0 + 1]);
    }
    __syncthreads();

    // ---- F6: FC 120 -> 84, tanh ----
    for (int it = tid; it < nimg * 84; it += 256) {
        int o   = it % 84;
        int img = it / 84;
        const float4* wv = (const float4*)(l1_w + o * 120);
        const float4* cv = (const float4*)(c5o_s + img * 120);
        v2f a2 = (v2f){0.0f, 0.0f};
        #pragma unroll
        for (int k = 0; k < 30; ++k) {
            float4 u = wv[k];
            float4 s = cv[k];
            a2 = fma2((v2f){s.x, s.y}, (v2f){u.x, u.y}, a2);
            a2 = fma2((v2f){s.z, s.w}, (v2f){u.z, u.w}, a2);
        }
        f6_s[img * 84 + o] = fast_tanh(a2.x + a2.y + l1_b[o]);
    }
    __syncthreads();

    // ---- Output: FC 84 -> 10 ----
    for (int it = tid; it < nimg * 10; it += 256) {
        int o   = it % 10;
        int img = it / 10;
        const float4* wv = (const float4*)(l2_w + o * 84);
        const float4* fv = (const float4*)(f6_s + img * 84);
        v2f a2 = (v2f){0.0f, 0.0f};
        #pragma unroll
        for (int k = 0; k < 21; ++k) {
            float4 u = wv[k];
            float4 s = fv[k];
            a2 = fma2((v2f){s.x, s.y}, (v2f){u.x, u.y}, a2);
            a2 = fma2((v2f){s.z, s.w}, (v2f){u.z, u.w}, a2);
        }
        out[(size_t)(img0 + img) * 10 + o] = a2.x + a2.y + l2_b[o];
    }
}

extern "C" void kernel_launch(void* const* d_in, const int* in_sizes, int n_in,
                              void* d_out, int out_size, void* d_ws, size_t ws_size,
                              hipStream_t stream) {
    const float* x     = (const float*)d_in[0];
    const float* c1_w  = (const float*)d_in[1];
    const float* c1_b  = (const float*)d_in[2];
    const float* c3_w3 = (const float*)d_in[3];
    const float* c3_b3 = (const float*)d_in[4];
    const float* c3_w4 = (const float*)d_in[5];
    const float* c3_b4 = (const float*)d_in[6];
    const float* c3_w6 = (const float*)d_in[7];
    const float* c3_b6 = (const float*)d_in[8];
    const float* c5_w  = (const float*)d_in[9];
    const float* c5_b  = (const float*)d_in[10];
    const float* l1_w  = (const float*)d_in[11];
    const float* l1_b  = (const float*)d_in[12];
    const float* l2_w  = (const float*)d_in[13];
    const float* l2_b  = (const float*)d_in[14];
    float* out = (float*)d_out;

    const int B = in_sizes[0] / 1024;   // [B,1,32,32]
    const int grid = (B + IMG - 1) / IMG;
    lenet_fused<<<grid, 256, 0, stream>>>(
        x, c1_w, c1_b, c3_w3, c3_b3, c3_w4, c3_b4, c3_w6, c3_b6,
        c5_w, c5_b, l1_w, l1_b, l2_w, l2_b, out, B);
}

// Round 5
// 308.906 us; speedup vs baseline: 1.1259x; 1.0177x over previous
//
#include <hip/hip_runtime.h>

typedef float v2f __attribute__((ext_vector_type(2)));

#define IMG 3
#define XSTR  34                 // even: b64-aligned rows; bank shift 2/row -> <=2-way
#define XIMG  (32 * XSTR)        // 1088
#define S2STR 18                 // even: b64 rows; banks 4i distinct for i in 0..4
#define S2MAP (14 * S2STR)       // 252
#define S2IMG (6 * S2MAP)        // 1512

// ---- LDS layout (floats) ----
// Region A [0..3376): phase1 = x (3 x 1088 = 3264)
//   phase2+ = c3w[0..1560) | s4 @1560 (1200) | c5o @2760 (360) | f6 @3120 (252)
#define S4_OFF   1560
#define C5O_OFF  2760
#define F6_OFF   3120
#define A_SIZE   3376
#define S2_OFF   A_SIZE                      // 3376, size 4536
#define C1W_OFF  (S2_OFF + IMG * S2IMG)      // 7912, 192 (6ch x 32: rows-of-6, padded)
#define C1B_OFF  (C1W_OFF + 192)             // 8104, 6 (+2)
#define C3B_OFF  (C1B_OFF + 8)               // 8112, 16
#define SMEM_FLOATS (C3B_OFF + 16)           // 8128 floats = 32512 B -> 5 blocks/CU

// ---- C3 sparse connectivity; weights as 60 chunks of 26 floats (padded) ----
__device__ __constant__ int C3_NCH[16]   = {3,3,3,3,3,3, 4,4,4,4,4,4,4,4,4, 6};
__device__ __constant__ int C3_CHUNK[16] = {0,3,6,9,12,15, 18,22,26,30,34,38,42,46,50, 54};
__device__ __constant__ int C3_CH[16][6] = {
    {0,1,2,0,0,0},{1,2,3,0,0,0},{2,3,4,0,0,0},{3,4,5,0,0,0},{0,4,5,0,0,0},{0,1,5,0,0,0},
    {0,1,2,3,0,0},{1,2,3,4,0,0},{2,3,4,5,0,0},{0,3,4,5,0,0},{0,1,4,5,0,0},
    {0,1,2,5,0,0},{0,1,3,4,0,0},{1,2,4,5,0,0},{0,2,3,5,0,0},
    {0,1,2,3,4,5}
};

__device__ __forceinline__ float fast_tanh(float x) {
    float e = __expf(2.0f * x);
    return fmaf(-2.0f, __builtin_amdgcn_rcpf(e + 1.0f), 1.0f);
}
__device__ __forceinline__ v2f fma2(v2f a, v2f b, v2f c) {
    return __builtin_elementwise_fma(a, b, c);
}

__global__ __launch_bounds__(256) void lenet_fused(
    const float* __restrict__ x,
    const float* __restrict__ c1_w,  const float* __restrict__ c1_b,
    const float* __restrict__ c3_w3, const float* __restrict__ c3_b3,
    const float* __restrict__ c3_w4, const float* __restrict__ c3_b4,
    const float* __restrict__ c3_w6, const float* __restrict__ c3_b6,
    const float* __restrict__ c5_w,  const float* __restrict__ c5_b,
    const float* __restrict__ l1_w,  const float* __restrict__ l1_b,
    const float* __restrict__ l2_w,  const float* __restrict__ l2_b,
    float* __restrict__ out, int B)
{
    __shared__ __align__(16) float smem[SMEM_FLOATS];
    float* x_s   = smem;                 // phase 1 only
    float* c3w_s = smem;                 // phase 2+ (aliases x_s)
    float* s4_s  = smem + S4_OFF;
    float* c5o_s = smem + C5O_OFF;
    float* f6_s  = smem + F6_OFF;
    float* s2_s  = smem + S2_OFF;
    float* c1w_s = smem + C1W_OFF;
    float* c1b_s = smem + C1B_OFF;
    float* c3b_s = smem + C3B_OFF;

    const int tid  = threadIdx.x;
    const int img0 = blockIdx.x * IMG;
    const int nimg = min(IMG, B - img0);
    if (nimg <= 0) return;

    // ---- prefetch c3 weights (padded-chunk layout) into regs; store post-C1 ----
    float c3wr[7];
    #pragma unroll
    for (int j = 0; j < 7; ++j) {
        int idx = tid + 256 * j;          // dst index in padded layout [0,1560)
        float v = 0.0f;
        if (idx < 1560) {
            int k = idx / 26, e = idx % 26;
            if (e < 25) {
                int src = k * 25 + e;
                if (src < 450)        v = c3_w3[src];
                else if (src < 1350)  v = c3_w4[src - 450];
                else                  v = c3_w6[src - 1350];
            }
        }
        c3wr[j] = v;
    }

    // ---- c1 weights: rows-of-6 padded layout [c][row(5+pad)][6] -> 32/ch ----
    if (tid < 192) {
        int c = tid >> 5, r = tid & 31;
        int row = r / 6, v = r % 6;
        c1w_s[tid] = (row < 5 && v < 5) ? c1_w[c * 25 + row * 5 + v] : 0.0f;
    }
    if (tid < 6) c1b_s[tid] = c1_b[tid];
    if (tid < 6)        c3b_s[tid] = c3_b3[tid];
    else if (tid < 15)  c3b_s[tid] = c3_b4[tid - 6];
    else if (tid == 15) c3b_s[15]  = c3_b6[0];

    // ---- stage x into LDS (float2 stores: 34-stride rows are 8B-aligned) ----
    {
        const float4* xg = (const float4*)(x + (size_t)img0 * 1024);
        const int n4 = nimg * 256;
        for (int i = tid; i < n4; i += 256) {
            float4 v = xg[i];
            int img = i >> 8, q = i & 255;
            int row = q >> 3, col4 = (q & 7) << 2;
            float* p = x_s + img * XIMG + row * XSTR + col4;
            *(float2*)(p)     = (float2){v.x, v.y};
            *(float2*)(p + 2) = (float2){v.z, v.w};
        }
    }
    __syncthreads();

    // ---- C1 + tanh + pool -> s2. item=(img,c,i,h). di-packed, b64 LDS reads ----
    for (int it = tid; it < nimg * 168; it += 256) {
        int h   = it & 1;
        int t2  = it >> 1;
        int i   = t2 % 14;
        int t3  = t2 / 14;
        int c   = t3 % 6;
        int img = t3 / 6;
        const float* xb = x_s + img * XIMG + 14 * h;
        const float* wb = c1w_s + c * 32;
        v2f acc2[14];
        #pragma unroll
        for (int j = 0; j < 14; ++j) acc2[j] = (v2f){0.0f, 0.0f};
        float wlo[5], whi[5];
        #pragma unroll
        for (int v = 0; v < 5; ++v) whi[v] = 0.0f;   // row xr-1 at xr=0
        #pragma unroll
        for (int xr = 0; xr < 6; ++xr) {
            // load weight row xr (zeros for xr=5)
            if (xr <= 4) {
                float2 w0 = *(const float2*)(wb + xr * 6);
                float2 w1 = *(const float2*)(wb + xr * 6 + 2);
                float2 w2 = *(const float2*)(wb + xr * 6 + 4);
                wlo[0] = w0.x; wlo[1] = w0.y; wlo[2] = w1.x; wlo[3] = w1.y; wlo[4] = w2.x;
            } else {
                #pragma unroll
                for (int v = 0; v < 5; ++v) wlo[v] = 0.0f;
            }
            // x row as 9 x b64
            float row[18];
            const float* rp = xb + (2 * i + xr) * XSTR;
            #pragma unroll
            for (int k = 0; k < 9; ++k) {
                float2 t = *(const float2*)(rp + 2 * k);
                row[2 * k] = t.x; row[2 * k + 1] = t.y;
            }
            v2f wp[5];
            #pragma unroll
            for (int v = 0; v < 5; ++v) wp[v] = (v2f){wlo[v], whi[v]};
            #pragma unroll
            for (int j = 0; j < 14; ++j) {
                acc2[j] = fma2((v2f){row[j],     row[j]},     wp[0], acc2[j]);
                acc2[j] = fma2((v2f){row[j + 1], row[j + 1]}, wp[1], acc2[j]);
                acc2[j] = fma2((v2f){row[j + 2], row[j + 2]}, wp[2], acc2[j]);
                acc2[j] = fma2((v2f){row[j + 3], row[j + 3]}, wp[3], acc2[j]);
                acc2[j] = fma2((v2f){row[j + 4], row[j + 4]}, wp[4], acc2[j]);
            }
            #pragma unroll
            for (int v = 0; v < 5; ++v) whi[v] = wlo[v];
        }
        const float b = c1b_s[c];
        float* o = s2_s + img * S2IMG + c * S2MAP + i * S2STR + 7 * h;
        #pragma unroll
        for (int j = 0; j < 7; ++j) {
            float t00 = fast_tanh(acc2[2 * j].x     + b);
            float t01 = fast_tanh(acc2[2 * j + 1].x + b);
            float t10 = fast_tanh(acc2[2 * j].y     + b);
            float t11 = fast_tanh(acc2[2 * j + 1].y + b);
            o[j] = 0.25f * (t00 + t01 + t10 + t11);
        }
    }
    __syncthreads();

    // ---- x_s dead: store c3 weights (padded layout) ----
    #pragma unroll
    for (int j = 0; j < 7; ++j) {
        int idx = tid + 256 * j;
        if (idx < 1560) c3w_s[idx] = c3wr[j];
    }
    __syncthreads();

    // ---- C3 sparse + tanh + pool -> s4. di-packed, b64 LDS reads ----
    for (int it = tid; it < nimg * 80; it += 256) {
        int i   = it % 5;
        int t2  = it / 5;
        int m   = t2 % 16;
        int img = t2 / 16;
        const int n = C3_NCH[m];
        const int ch0 = C3_CHUNK[m];
        v2f acc2[10];
        #pragma unroll
        for (int j = 0; j < 10; ++j) acc2[j] = (v2f){0.0f, 0.0f};
        for (int cc = 0; cc < n; ++cc) {
            const int c = C3_CH[m][cc];
            const float* wc = c3w_s + (ch0 + cc) * 26;
            float w[25];
            #pragma unroll
            for (int k = 0; k < 12; ++k) {
                float2 t = *(const float2*)(wc + 2 * k);
                w[2 * k] = t.x; w[2 * k + 1] = t.y;
            }
            w[24] = wc[24];
            const float* sb = s2_s + img * S2IMG + c * S2MAP;
            #pragma unroll
            for (int xr = 0; xr < 6; ++xr) {
                float row[14];
                const float* rp = sb + (2 * i + xr) * S2STR;
                #pragma unroll
                for (int k = 0; k < 7; ++k) {
                    float2 t = *(const float2*)(rp + 2 * k);
                    row[2 * k] = t.x; row[2 * k + 1] = t.y;
                }
                v2f wp[5];
                #pragma unroll
                for (int v = 0; v < 5; ++v) {
                    wp[v].x = (xr <= 4) ? w[xr * 5 + v]       : 0.0f;
                    wp[v].y = (xr >= 1) ? w[(xr - 1) * 5 + v] : 0.0f;
                }
                #pragma unroll
                for (int j = 0; j < 10; ++j) {
                    acc2[j] = fma2((v2f){row[j],     row[j]},     wp[0], acc2[j]);
                    acc2[j] = fma2((v2f){row[j + 1], row[j + 1]}, wp[1], acc2[j]);
                    acc2[j] = fma2((v2f){row[j + 2], row[j + 2]}, wp[2], acc2[j]);
                    acc2[j] = fma2((v2f){row[j + 3], row[j + 3]}, wp[3], acc2[j]);
                    acc2[j] = fma2((v2f){row[j + 4], row[j + 4]}, wp[4], acc2[j]);
                }
            }
        }
        const float b = c3b_s[m];
        float* o = s4_s + img * 400 + m * 25 + i * 5;
        #pragma unroll
        for (int j = 0; j < 5; ++j) {
            float t00 = fast_tanh(acc2[2 * j].x     + b);
            float t01 = fast_tanh(acc2[2 * j + 1].x + b);
            float t10 = fast_tanh(acc2[2 * j].y     + b);
            float t11 = fast_tanh(acc2[2 * j + 1].y + b);
            o[j] = 0.25f * (t00 + t01 + t10 + t11);
        }
    }
    __syncthreads();

    // ---- C5: FC 400 -> 120, tanh ----
    for (int it = tid; it < nimg * 60; it += 256) {
        int op  = it % 60;
        int img = it / 60;
        int o0  = op * 2;
        const float4* wa = (const float4*)(c5_w + (size_t)o0 * 400);
        const float4* wb = (const float4*)(c5_w + (size_t)o0 * 400 + 400);
        const float4* sv = (const float4*)(s4_s + img * 400);
        v2f a2 = (v2f){0.0f, 0.0f}, b2 = (v2f){0.0f, 0.0f};
        #pragma unroll 4
        for (int k = 0; k < 100; ++k) {
            float4 s = sv[k];
            float4 u = wa[k];
            float4 v = wb[k];
            v2f slo = {s.x, s.y}, shi = {s.z, s.w};
            a2 = fma2(slo, (v2f){u.x, u.y}, a2);
            a2 = fma2(shi, (v2f){u.z, u.w}, a2);
            b2 = fma2(slo, (v2f){v.x, v.y}, b2);
            b2 = fma2(shi, (v2f){v.z, v.w}, b2);
        }
        c5o_s[img * 120 + o0]     = fast_tanh(a2.x + a2.y + c5_b[o0]);
        c5o_s[img * 120 + o0 + 1] = fast_tanh(b2.x + b2.y + c5_b[o0 + 1]);
    }
    __syncthreads();

    // ---- F6: FC 120 -> 84, tanh ----
    for (int it = tid; it < nimg * 84; it += 256) {
        int o   = it % 84;
        int img = it / 84;
        const float4* wv = (const float4*)(l1_w + o * 120);
        const float4* cv = (const float4*)(c5o_s + img * 120);
        v2f a2 = (v2f){0.0f, 0.0f};
        #pragma unroll
        for (int k = 0; k < 30; ++k) {
            float4 u = wv[k];
            float4 s = cv[k];
            a2 = fma2((v2f){s.x, s.y}, (v2f){u.x, u.y}, a2);
            a2 = fma2((v2f){s.z, s.w}, (v2f){u.z, u.w}, a2);
        }
        f6_s[img * 84 + o] = fast_tanh(a2.x + a2.y + l1_b[o]);
    }
    __syncthreads();

    // ---- Output: FC 84 -> 10 ----
    for (int it = tid; it < nimg * 10; it += 256) {
        int o   = it % 10;
        int img = it / 10;
        const float4* wv = (const float4*)(l2_w + o * 84);
        const float4* fv = (const float4*)(f6_s + img * 84);
        v2f a2 = (v2f){0.0f, 0.0f};
        #pragma unroll
        for (int k = 0; k < 21; ++k) {
            float4 u = wv[k];
            float4 s = fv[k];
            a2 = fma2((v2f){s.x, s.y}, (v2f){u.x, u.y}, a2);
            a2 = fma2((v2f){s.z, s.w}, (v2f){u.z, u.w}, a2);
        }
        out[(size_t)(img0 + img) * 10 + o] = a2.x + a2.y + l2_b[o];
    }
}

extern "C" void kernel_launch(void* const* d_in, const int* in_sizes, int n_in,
                              void* d_out, int out_size, void* d_ws, size_t ws_size,
                              hipStream_t stream) {
    const float* x     = (const float*)d_in[0];
    const float* c1_w  = (const float*)d_in[1];
    const float* c1_b  = (const float*)d_in[2];
    const float* c3_w3 = (const float*)d_in[3];
    const float* c3_b3 = (const float*)d_in[4];
    const float* c3_w4 = (const float*)d_in[5];
    const float* c3_b4 = (const float*)d_in[6];
    const float* c3_w6 = (const float*)d_in[7];
    const float* c3_b6 = (const float*)d_in[8];
    const float* c5_w  = (const float*)d_in[9];
    const float* c5_b  = (const float*)d_in[10];
    const float* l1_w  = (const float*)d_in[11];
    const float* l1_b  = (const float*)d_in[12];
    const float* l2_w  = (const float*)d_in[13];
    const float* l2_b  = (const float*)d_in[14];
    float* out = (float*)d_out;

    const int B = in_sizes[0] / 1024;   // [B,1,32,32]
    const int grid = (B + IMG - 1) / IMG;
    lenet_fused<<<grid, 256, 0, stream>>>(
        x, c1_w, c1_b, c3_w3, c3_b3, c3_w4, c3_b4, c3_w6, c3_b6,
        c5_w, c5_b, l1_w, l1_b, l2_w, l2_b, out, B);
}